// Round 5
// baseline (329.888 us; speedup 1.0000x reference)
//
#include <hip/hip_runtime.h>
#include <hip/hip_bf16.h>

// RoIAlign (avg, aligned=True).
//   input: (4, 256, 200, 200) fp32, rois: (1024, 5) fp32
//   pooled 7x7, sampling_ratio=2, spatial_scale=0.25
//   out: (1024, 256, 7, 7) fp32
//
// R4: grouped-64 bf16 layout ws[b][g][y][x][64c] — one pixel's group =
// 128 B = one L2 line. Gather wave = 8 bins x 8 slices: each corner
// wave-load coalesces to 8 contiguous 128-B segments (was 16x64B in R2/R3).
// Keeps R3's ROI counting-sort + XCD swizzle.

#define CCH 256
#define FH 200
#define FW 200
#define N_ROIS 1024
#define PP 49          // 7*7 bins
#define NG 4           // channel groups (256/64)
#define GSZ 64         // channels per group
#define PLANE (FH*FW)

// ---------- pass 0: counting-sort ROIs by image index ----------
__global__ __launch_bounds__(1024) void sort_rois(
    const float* __restrict__ rois, int* __restrict__ perm)
{
    __shared__ int cnt[4];
    __shared__ int base[4];
    int t = threadIdx.x;                 // 1024 threads, one block
    if (t < 4) cnt[t] = 0;
    __syncthreads();
    int b = (int)rois[t * 5];
    int pos = atomicAdd(&cnt[b], 1);
    __syncthreads();
    if (t == 0) {
        int s = 0;
        #pragma unroll
        for (int i = 0; i < 4; ++i) { base[i] = s; s += cnt[i]; }
    }
    __syncthreads();
    perm[base[b] + pos] = t;
}

// ---------- pass 1: NCHW fp32 -> grouped-64 bf16 ----------
__global__ __launch_bounds__(256) void to_grouped(
    const float* __restrict__ in, unsigned short* __restrict__ gout)
{
    int idx = blockIdx.x * 256 + threadIdx.x;   // 4*4*40000 = 640,000 exact
    int p  = idx % PLANE;
    int bg = idx / PLANE;                       // b*4+g ; c_base = 64*bg
    const float* src = in + (size_t)bg * GSZ * PLANE + p;

    unsigned short tmp[GSZ];
    #pragma unroll
    for (int j = 0; j < GSZ; ++j) {
        unsigned u = __float_as_uint(src[(size_t)j * PLANE]);
        tmp[j] = (unsigned short)((u + 0x7FFFu + ((u >> 16) & 1u)) >> 16); // RNE
    }
    uint4* dst = (uint4*)(gout + (size_t)idx * GSZ);
    #pragma unroll
    for (int k = 0; k < 8; ++k) {
        uint4 q;
        __builtin_memcpy(&q, &tmp[k * 8], 16);
        dst[k] = q;
    }
}

// ---------- pass 2: gather ----------
__device__ __forceinline__ void fma8(float* acc, const unsigned short* p, float w)
{
    uint4 q = *(const uint4*)p;                 // 8 bf16
    unsigned short u[8];
    __builtin_memcpy(u, &q, 16);
    #pragma unroll
    for (int j = 0; j < 8; ++j)
        acc[j] = fmaf(w, __uint_as_float((unsigned)u[j] << 16), acc[j]);
}

__global__ __launch_bounds__(256) void roi_align_grouped(
    const unsigned short* __restrict__ gfeat,
    const float* __restrict__ rois,
    const int* __restrict__ perm,
    float* __restrict__ out)
{
    // XCD swizzle: consecutive virtual blocks on one XCD; g outermost.
    int nb  = gridDim.x;                         // 6272, divisible by 8
    int vb  = (blockIdx.x & 7) * (nb >> 3) + (blockIdx.x >> 3);
    int idx = vb * 256 + threadIdx.x;            // 4*1024*49*8 exact

    int s      = idx & 7;                        // 8-channel slice (16 B)
    int bin    = (idx >> 3) % PP;
    int n_slot = (idx / (8 * PP)) % N_ROIS;      // sorted position
    int g      = idx / (8 * PP * N_ROIS);
    int n      = perm[n_slot];                   // original ROI id
    int ph = bin / 7, pw = bin % 7;

    const float* roi = rois + n * 5;
    int   b  = (int)roi[0];
    float x1 = roi[1] * 0.25f - 0.5f;
    float y1 = roi[2] * 0.25f - 0.5f;
    float x2 = roi[3] * 0.25f - 0.5f;
    float y2 = roi[4] * 0.25f - 0.5f;
    float bin_h = (y2 - y1) / 7.0f;
    float bin_w = (x2 - x1) / 7.0f;

    const unsigned short* plane =
        gfeat + (size_t)(b * NG + g) * PLANE * GSZ + s * 8;

    float acc[8] = {0, 0, 0, 0, 0, 0, 0, 0};

    #pragma unroll
    for (int iy = 0; iy < 2; ++iy) {
        float y = y1 + ((float)ph + ((float)iy + 0.5f) * 0.5f) * bin_h;
        if (y < -1.0f || y > (float)FH) continue;
        float yc  = fminf(fmaxf(y, 0.0f), (float)(FH - 1));
        int   y0  = (int)yc;
        int   y1i = min(y0 + 1, FH - 1);
        float ly  = yc - (float)y0;
        float hy  = 1.0f - ly;

        #pragma unroll
        for (int ix = 0; ix < 2; ++ix) {
            float x = x1 + ((float)pw + ((float)ix + 0.5f) * 0.5f) * bin_w;
            if (x < -1.0f || x > (float)FW) continue;
            float xc  = fminf(fmaxf(x, 0.0f), (float)(FW - 1));
            int   x0  = (int)xc;
            int   x1i = min(x0 + 1, FW - 1);
            float lx  = xc - (float)x0;
            float hx  = 1.0f - lx;

            const unsigned short* r0 = plane + (size_t)(y0  * FW) * GSZ;
            const unsigned short* r1 = plane + (size_t)(y1i * FW) * GSZ;
            fma8(acc, r0 + (size_t)x0  * GSZ, hy * hx);
            fma8(acc, r0 + (size_t)x1i * GSZ, hy * lx);
            fma8(acc, r1 + (size_t)x0  * GSZ, ly * hx);
            fma8(acc, r1 + (size_t)x1i * GSZ, ly * lx);
        }
    }

    // out[n][c][bin], c = g*64 + s*8 + j
    float* o = out + ((size_t)n * CCH + g * GSZ + s * 8) * PP + bin;
    #pragma unroll
    for (int j = 0; j < 8; ++j)
        o[j * PP] = acc[j] * 0.25f;
}

// ---------- fallback (R1 kernel) if ws too small ----------
__global__ __launch_bounds__(256) void roi_align_fallback(
    const float* __restrict__ feat, const float* __restrict__ rois,
    float* __restrict__ out, int total)
{
    int nb  = gridDim.x;
    int vid = (blockIdx.x & 7) * (nb >> 3) + (blockIdx.x >> 3);
    int idx = vid * 256 + threadIdx.x;
    if (idx >= total) return;
    int pw = idx % 7;
    int ph = (idx / 7) % 7;
    int n  = (idx / 49) & (N_ROIS - 1);
    int c  = idx / (49 * N_ROIS);

    const float* roi = rois + n * 5;
    int   b  = (int)roi[0];
    float x1 = roi[1] * 0.25f - 0.5f;
    float y1 = roi[2] * 0.25f - 0.5f;
    float x2 = roi[3] * 0.25f - 0.5f;
    float y2 = roi[4] * 0.25f - 0.5f;
    float bin_h = (y2 - y1) / 7.0f;
    float bin_w = (x2 - x1) / 7.0f;
    const float* plane = feat + ((size_t)b * CCH + c) * PLANE;

    float acc = 0.0f;
    #pragma unroll
    for (int iy = 0; iy < 2; ++iy) {
        float y = y1 + ((float)ph + ((float)iy + 0.5f) * 0.5f) * bin_h;
        if (y < -1.0f || y > (float)FH) continue;
        float yc = fminf(fmaxf(y, 0.0f), (float)(FH - 1));
        int y0 = (int)yc, y1i = min(y0 + 1, FH - 1);
        float ly = yc - (float)y0, hy = 1.0f - ly;
        #pragma unroll
        for (int ix = 0; ix < 2; ++ix) {
            float x = x1 + ((float)pw + ((float)ix + 0.5f) * 0.5f) * bin_w;
            if (x < -1.0f || x > (float)FW) continue;
            float xc = fminf(fmaxf(x, 0.0f), (float)(FW - 1));
            int x0 = (int)xc, x1i = min(x0 + 1, FW - 1);
            float lx = xc - (float)x0, hx = 1.0f - lx;
            acc += hy * (hx * plane[y0 * FW + x0] + lx * plane[y0 * FW + x1i])
                 + ly * (hx * plane[y1i * FW + x0] + lx * plane[y1i * FW + x1i]);
        }
    }
    out[((size_t)n * CCH + c) * PP + ph * 7 + pw] = acc * 0.25f;
}

extern "C" void kernel_launch(void* const* d_in, const int* in_sizes, int n_in,
                              void* d_out, int out_size, void* d_ws, size_t ws_size,
                              hipStream_t stream)
{
    const float* feat = (const float*)d_in[0];
    const float* rois = (const float*)d_in[1];
    float* out = (float*)d_out;

    const size_t gfeat_bytes = (size_t)4 * NG * PLANE * GSZ * 2;  // 81.92 MB
    const size_t ws_needed = gfeat_bytes + N_ROIS * sizeof(int);

    if (ws_size >= ws_needed) {
        unsigned short* gfeat = (unsigned short*)d_ws;
        int* perm = (int*)((char*)d_ws + gfeat_bytes);
        sort_rois<<<1, 1024, 0, stream>>>(rois, perm);
        to_grouped<<<(4 * NG * PLANE) / 256, 256, 0, stream>>>(feat, gfeat);
        int items = NG * N_ROIS * PP * 8;            // 1,605,632
        roi_align_grouped<<<items / 256, 256, 0, stream>>>(gfeat, rois, perm, out);
    } else {
        int total = out_size;
        int grid = (total + 255) / 256;
        roi_align_fallback<<<grid, 256, 0, stream>>>(feat, rois, out, total);
    }
}